// Round 1
// baseline (5668.725 us; speedup 1.0000x reference)
//
#include <hip/hip_runtime.h>
#include <cstddef>

#define NNODES 50000
#define NEDGES 800000
#define FDIM   256

__device__ __forceinline__ void atomAddF(float* p, float v) {
#if defined(__HIP_PLATFORM_AMD__)
    unsafeAtomicAdd(p, v);
#else
    atomicAdd(p, v);
#endif
}

__device__ __forceinline__ float leaky_exp(float a) {
    float e = a > 0.f ? a : 0.2f * a;
    return expf(e);
}

// ---------------- GEMM: C[M,256] = A[M,256] @ B[256,256], fp32 ----------------
__global__ __launch_bounds__(256) void gemm256(const float* __restrict__ A,
                                               const float* __restrict__ B,
                                               float* __restrict__ C, int M) {
    __shared__ float As[16][68];   // [k][m], padded to keep 16B alignment, no conflicts
    __shared__ float Bs[16][68];   // [k][n]
    const int t  = threadIdx.x;
    const int bm = blockIdx.x * 64;
    const int bn = blockIdx.y * 64;
    const int tm = (t >> 4) << 2;       // 0..60
    const int tn = (t & 15) << 2;       // 0..60
    const int ar = t >> 2;              // 0..63 (row in A tile)
    const int ac = (t & 3) << 2;        // 0,4,8,12 (k in A tile)
    const int br = t >> 4;              // 0..15 (k in B tile)
    const int bc = (t & 15) << 2;       // 0..60 (col in B tile)
    float acc[4][4] = {};
    for (int k0 = 0; k0 < 256; k0 += 16) {
        float4 a4 = make_float4(0.f, 0.f, 0.f, 0.f);
        if (bm + ar < M)
            a4 = *(const float4*)(A + (size_t)(bm + ar) * FDIM + k0 + ac);
        As[ac + 0][ar] = a4.x; As[ac + 1][ar] = a4.y;
        As[ac + 2][ar] = a4.z; As[ac + 3][ar] = a4.w;
        *(float4*)(&Bs[br][bc]) =
            *(const float4*)(B + (size_t)(k0 + br) * FDIM + bn + bc);
        __syncthreads();
#pragma unroll
        for (int k = 0; k < 16; ++k) {
            float4 av = *(const float4*)(&As[k][tm]);
            float4 bv = *(const float4*)(&Bs[k][tn]);
            float aa[4] = {av.x, av.y, av.z, av.w};
            float bb[4] = {bv.x, bv.y, bv.z, bv.w};
#pragma unroll
            for (int i = 0; i < 4; ++i)
#pragma unroll
                for (int j = 0; j < 4; ++j) acc[i][j] += aa[i] * bb[j];
        }
        __syncthreads();
    }
#pragma unroll
    for (int i = 0; i < 4; ++i) {
        int row = bm + tm + i;
        if (row < M)
            *(float4*)(C + (size_t)row * FDIM + bn + tn) =
                make_float4(acc[i][0], acc[i][1], acc[i][2], acc[i][3]);
    }
}

// ------------- attention logits: a_src[n,h], a_dst[n,h]; wave per node -------------
template <int H>
__global__ __launch_bounds__(256) void aprep_k(const float* __restrict__ xp,
                                               const float* __restrict__ atts,
                                               const float* __restrict__ attd,
                                               float* __restrict__ as_,
                                               float* __restrict__ ad_) {
    const int lane = threadIdx.x & 63;
    const int n = blockIdx.x * 4 + (threadIdx.x >> 6);
    if (n >= NNODES) return;
    const int c = lane << 2;
    float4 v  = *(const float4*)(xp + (size_t)n * FDIM + c);
    float4 s4 = *(const float4*)(atts + c);
    float4 d4 = *(const float4*)(attd + c);
    float ss = v.x * s4.x + v.y * s4.y + v.z * s4.z + v.w * s4.w;
    float sd = v.x * d4.x + v.y * d4.y + v.z * d4.z + v.w * d4.w;
    constexpr int G = 64 / H;   // lanes per head
#pragma unroll
    for (int off = 1; off < G; off <<= 1) {
        ss += __shfl_xor(ss, off);
        sd += __shfl_xor(sd, off);
    }
    if ((lane & (G - 1)) == 0) {
        int h = lane / G;
        as_[n * H + h] = ss;
        ad_[n * H + h] = sd;
    }
}

// ------------- edge scatter: agg[dst] += w * xp[src]; denom[dst] += w -------------
template <int H>
__global__ __launch_bounds__(256) void edge_k(const float* __restrict__ xp,
                                              const float* __restrict__ as_,
                                              const float* __restrict__ ad_,
                                              const int* __restrict__ ei,
                                              float* __restrict__ agg,
                                              float* __restrict__ den) {
    const int lane = threadIdx.x & 63;
    const int e = blockIdx.x * 4 + (threadIdx.x >> 6);
    if (e >= NEDGES) return;
    const int s = ei[e];
    const int d = ei[NEDGES + e];
    constexpr int G = 64 / H;
    const int h = lane / G;
    float w = leaky_exp(as_[s * H + h] + ad_[d * H + h]);
    const int c = lane << 2;
    float4 v = *(const float4*)(xp + (size_t)s * FDIM + c);
    float* dst = agg + (size_t)d * FDIM + c;
    atomAddF(dst + 0, w * v.x);
    atomAddF(dst + 1, w * v.y);
    atomAddF(dst + 2, w * v.z);
    atomAddF(dst + 3, w * v.w);
    if ((lane & (G - 1)) == 0) atomAddF(den + d * H + h, w);
}

// ------- layer-1 epilogue: add self-loop, normalize, +bias, ELU (in place) -------
__global__ __launch_bounds__(256) void norm1_k(float* __restrict__ aggh,
                                               const float* __restrict__ xp,
                                               const float* __restrict__ as_,
                                               const float* __restrict__ ad_,
                                               const float* __restrict__ den,
                                               const float* __restrict__ bias) {
    const int n = blockIdx.x;
    const int t = threadIdx.x;
    const int h = t >> 6;
    float w  = leaky_exp(as_[n * 4 + h] + ad_[n * 4 + h]);
    size_t idx = (size_t)n * FDIM + t;
    float num = aggh[idx] + w * xp[idx];
    float dn  = den[n * 4 + h] + w + 1e-16f;
    float o = num / dn + bias[t];
    aggh[idx] = o > 0.f ? o : expf(o) - 1.f;
}

// --- layer-2 epilogue fused with BN + LN; wave per node; in-place on d_out ---
__global__ __launch_bounds__(256) void final_k(float* __restrict__ agg_out,
                                               const float* __restrict__ xp,
                                               const float* __restrict__ as_,
                                               const float* __restrict__ ad_,
                                               const float* __restrict__ den,
                                               const float* __restrict__ bias,
                                               const float* __restrict__ bng,
                                               const float* __restrict__ bnb,
                                               const float* __restrict__ bnm,
                                               const float* __restrict__ bnv,
                                               const float* __restrict__ lng,
                                               const float* __restrict__ lnb) {
    const int lane = threadIdx.x & 63;
    const int n = blockIdx.x * 4 + (threadIdx.x >> 6);
    if (n >= NNODES) return;
    float w  = leaky_exp(as_[n] + ad_[n]);
    float dn = den[n] + w + 1e-16f;
    const int c = lane << 2;
    size_t base = (size_t)n * FDIM + c;
    float4 g = *(const float4*)(agg_out + base);
    float4 v = *(const float4*)(xp + base);
    float vals[4] = {(g.x + w * v.x) / dn, (g.y + w * v.y) / dn,
                     (g.z + w * v.z) / dn, (g.w + w * v.w) / dn};
#pragma unroll
    for (int j = 0; j < 4; ++j) {
        float o = vals[j] + bias[c + j];
        o = o > 0.f ? o : expf(o) - 1.f;                              // ELU
        o = (o - bnm[c + j]) * rsqrtf(bnv[c + j] + 1e-5f) * bng[c + j]
            + bnb[c + j];                                             // BN (eval)
        vals[j] = o;
    }
    float s1 = vals[0] + vals[1] + vals[2] + vals[3];
    float s2 = vals[0] * vals[0] + vals[1] * vals[1] +
               vals[2] * vals[2] + vals[3] * vals[3];
#pragma unroll
    for (int off = 1; off < 64; off <<= 1) {
        s1 += __shfl_xor(s1, off);
        s2 += __shfl_xor(s2, off);
    }
    float mu  = s1 * (1.f / 256.f);
    float var = s2 * (1.f / 256.f) - mu * mu;
    float r   = rsqrtf(var + 1e-5f);
#pragma unroll
    for (int j = 0; j < 4; ++j)
        agg_out[base + j] = (vals[j] - mu) * r * lng[c + j] + lnb[c + j];
}

extern "C" void kernel_launch(void* const* d_in, const int* in_sizes, int n_in,
                              void* d_out, int out_size, void* d_ws, size_t ws_size,
                              hipStream_t stream) {
    const float* x      = (const float*)d_in[0];
    const int*   ei     = (const int*)d_in[1];
    const float* W1     = (const float*)d_in[2];
    const float* atts1  = (const float*)d_in[3];
    const float* attd1  = (const float*)d_in[4];
    const float* bias1  = (const float*)d_in[5];
    const float* W2     = (const float*)d_in[6];
    const float* atts2  = (const float*)d_in[7];
    const float* attd2  = (const float*)d_in[8];
    const float* bias2  = (const float*)d_in[9];
    const float* bng    = (const float*)d_in[10];
    const float* bnb    = (const float*)d_in[11];
    const float* bnm    = (const float*)d_in[12];
    const float* bnv    = (const float*)d_in[13];
    const float* lng    = (const float*)d_in[14];
    const float* lnb    = (const float*)d_in[15];

    float* xp   = (float*)d_ws;                       // N*256 floats (51.2 MB)
    float* as1  = xp + (size_t)NNODES * FDIM;
    float* ad1  = as1 + (size_t)NNODES * 4;
    float* dn1  = ad1 + (size_t)NNODES * 4;
    float* as2  = dn1 + (size_t)NNODES * 4;
    float* ad2  = as2 + (size_t)NNODES;
    float* dn2  = ad2 + (size_t)NNODES;
    float* hbuf = (float*)d_out;                      // agg1 / h1 / agg2 / output

    const dim3 gemm_grid((NNODES + 63) / 64, 4);
    const int node_wave_blocks = (NNODES + 3) / 4;    // 4 waves/block, wave per node
    const int edge_blocks = (NEDGES + 3) / 4;

    // ---- layer 1 ----
    gemm256<<<gemm_grid, 256, 0, stream>>>(x, W1, xp, NNODES);
    aprep_k<4><<<node_wave_blocks, 256, 0, stream>>>(xp, atts1, attd1, as1, ad1);
    hipMemsetAsync(hbuf, 0, (size_t)NNODES * FDIM * sizeof(float), stream);
    hipMemsetAsync(dn1, 0, (size_t)NNODES * 4 * sizeof(float), stream);
    edge_k<4><<<edge_blocks, 256, 0, stream>>>(xp, as1, ad1, ei, hbuf, dn1);
    norm1_k<<<NNODES, 256, 0, stream>>>(hbuf, xp, as1, ad1, dn1, bias1);

    // ---- layer 2 ----
    gemm256<<<gemm_grid, 256, 0, stream>>>(hbuf, W2, xp, NNODES);
    aprep_k<1><<<node_wave_blocks, 256, 0, stream>>>(xp, atts2, attd2, as2, ad2);
    hipMemsetAsync(hbuf, 0, (size_t)NNODES * FDIM * sizeof(float), stream);
    hipMemsetAsync(dn2, 0, (size_t)NNODES * sizeof(float), stream);
    edge_k<1><<<edge_blocks, 256, 0, stream>>>(xp, as2, ad2, ei, hbuf, dn2);
    final_k<<<node_wave_blocks, 256, 0, stream>>>(hbuf, xp, as2, ad2, dn2, bias2,
                                                  bng, bnb, bnm, bnv, lng, lnb);
}

// Round 2
// 623.554 us; speedup vs baseline: 9.0910x; 9.0910x over previous
//
#include <hip/hip_runtime.h>
#include <cstddef>

#define NNODES 50000
#define NEDGES 800000
#define FDIM   256

__device__ __forceinline__ float leaky_exp(float a) {
    float e = a > 0.f ? a : 0.2f * a;
    return expf(e);
}

// ---------------- GEMM: C[M,256] = A[M,256] @ B[256,256], fp32 ----------------
__global__ __launch_bounds__(256) void gemm256(const float* __restrict__ A,
                                               const float* __restrict__ B,
                                               float* __restrict__ C, int M) {
    __shared__ float As[16][68];
    __shared__ float Bs[16][68];
    const int t  = threadIdx.x;
    const int bm = blockIdx.x * 64;
    const int bn = blockIdx.y * 64;
    const int tm = (t >> 4) << 2;
    const int tn = (t & 15) << 2;
    const int ar = t >> 2;
    const int ac = (t & 3) << 2;
    const int br = t >> 4;
    const int bc = (t & 15) << 2;
    float acc[4][4] = {};
    for (int k0 = 0; k0 < 256; k0 += 16) {
        float4 a4 = make_float4(0.f, 0.f, 0.f, 0.f);
        if (bm + ar < M)
            a4 = *(const float4*)(A + (size_t)(bm + ar) * FDIM + k0 + ac);
        As[ac + 0][ar] = a4.x; As[ac + 1][ar] = a4.y;
        As[ac + 2][ar] = a4.z; As[ac + 3][ar] = a4.w;
        *(float4*)(&Bs[br][bc]) =
            *(const float4*)(B + (size_t)(k0 + br) * FDIM + bn + bc);
        __syncthreads();
#pragma unroll
        for (int k = 0; k < 16; ++k) {
            float4 av = *(const float4*)(&As[k][tm]);
            float4 bv = *(const float4*)(&Bs[k][tn]);
            float aa[4] = {av.x, av.y, av.z, av.w};
            float bb[4] = {bv.x, bv.y, bv.z, bv.w};
#pragma unroll
            for (int i = 0; i < 4; ++i)
#pragma unroll
                for (int j = 0; j < 4; ++j) acc[i][j] += aa[i] * bb[j];
        }
        __syncthreads();
    }
#pragma unroll
    for (int i = 0; i < 4; ++i) {
        int row = bm + tm + i;
        if (row < M)
            *(float4*)(C + (size_t)row * FDIM + bn + tn) =
                make_float4(acc[i][0], acc[i][1], acc[i][2], acc[i][3]);
    }
}

// ------------- attention logits: a_src[n,h], a_dst[n,h]; wave per node -------------
template <int H>
__global__ __launch_bounds__(256) void aprep_k(const float* __restrict__ xp,
                                               const float* __restrict__ atts,
                                               const float* __restrict__ attd,
                                               float* __restrict__ as_,
                                               float* __restrict__ ad_) {
    const int lane = threadIdx.x & 63;
    const int n = blockIdx.x * 4 + (threadIdx.x >> 6);
    if (n >= NNODES) return;
    const int c = lane << 2;
    float4 v  = *(const float4*)(xp + (size_t)n * FDIM + c);
    float4 s4 = *(const float4*)(atts + c);
    float4 d4 = *(const float4*)(attd + c);
    float ss = v.x * s4.x + v.y * s4.y + v.z * s4.z + v.w * s4.w;
    float sd = v.x * d4.x + v.y * d4.y + v.z * d4.z + v.w * d4.w;
    constexpr int G = 64 / H;
#pragma unroll
    for (int off = 1; off < G; off <<= 1) {
        ss += __shfl_xor(ss, off);
        sd += __shfl_xor(sd, off);
    }
    if ((lane & (G - 1)) == 0) {
        int h = lane / G;
        as_[n * H + h] = ss;
        ad_[n * H + h] = sd;
    }
}

// ---------------- CSR build: histogram -> scan -> scatter ----------------
__global__ __launch_bounds__(256) void hist_k(const int* __restrict__ ei,
                                              int* __restrict__ deg) {
    int e = blockIdx.x * 256 + threadIdx.x;
    if (e < NEDGES) atomicAdd(&deg[ei[NEDGES + e]], 1);
}

__global__ __launch_bounds__(1024) void scan_k(const int* __restrict__ deg,
                                               int* __restrict__ rowptr) {
    const int t = threadIdx.x;
    const int CHUNK = (NNODES + 1023) / 1024;      // 49
    const int lo = t * CHUNK;
    const int hi = min(lo + CHUNK, NNODES);
    int sum = 0;
    for (int i = lo; i < hi; ++i) sum += deg[i];
    const int lane = t & 63, wid = t >> 6;
    int v = sum;
#pragma unroll
    for (int off = 1; off < 64; off <<= 1) {
        int u = __shfl_up(v, off);
        if (lane >= off) v += u;
    }
    __shared__ int wsum[16], woff[16];
    if (lane == 63) wsum[wid] = v;
    __syncthreads();
    if (t == 0) {
        int acc = 0;
        for (int i = 0; i < 16; ++i) { woff[i] = acc; acc += wsum[i]; }
        rowptr[NNODES] = acc;
    }
    __syncthreads();
    int excl = woff[wid] + (v - sum);
    for (int i = lo; i < hi; ++i) { rowptr[i] = excl; excl += deg[i]; }
}

// consumes deg as a countdown cursor (deg destroyed)
__global__ __launch_bounds__(256) void scatter_k(const int* __restrict__ ei,
                                                 const int* __restrict__ rowptr,
                                                 int* __restrict__ deg,
                                                 int* __restrict__ ssrc) {
    int e = blockIdx.x * 256 + threadIdx.x;
    if (e >= NEDGES) return;
    int s = ei[e], d = ei[NEDGES + e];
    int old = atomicSub(&deg[d], 1);
    ssrc[rowptr[d + 1] - old] = s;
}

// ---- layer-1 gather: wave per node, registers accumulate, ELU+bias epilogue ----
__global__ __launch_bounds__(256) void gather1_k(const float* __restrict__ xp,
                                                 const float* __restrict__ as_,
                                                 const float* __restrict__ ad_,
                                                 const int* __restrict__ rowptr,
                                                 const int* __restrict__ ssrc,
                                                 const float* __restrict__ bias,
                                                 float* __restrict__ out) {
    const int lane = threadIdx.x & 63;
    const int n = blockIdx.x * 4 + (threadIdx.x >> 6);
    if (n >= NNODES) return;
    const int h = lane >> 4;          // head (64 feats per head)
    const int c = lane << 2;
    const float adn = ad_[n * 4 + h];
    float4 acc = make_float4(0.f, 0.f, 0.f, 0.f);
    float den = 0.f;
    const int beg = rowptr[n], end = rowptr[n + 1];
    int e = beg;
    for (; e + 2 <= end; e += 2) {
        int s0 = ssrc[e], s1 = ssrc[e + 1];
        float a0 = as_[s0 * 4 + h], a1 = as_[s1 * 4 + h];
        float4 v0 = *(const float4*)(xp + (size_t)s0 * FDIM + c);
        float4 v1 = *(const float4*)(xp + (size_t)s1 * FDIM + c);
        float w0 = leaky_exp(a0 + adn), w1 = leaky_exp(a1 + adn);
        acc.x += w0 * v0.x + w1 * v1.x;
        acc.y += w0 * v0.y + w1 * v1.y;
        acc.z += w0 * v0.z + w1 * v1.z;
        acc.w += w0 * v0.w + w1 * v1.w;
        den += w0 + w1;
    }
    if (e < end) {
        int s0 = ssrc[e];
        float w0 = leaky_exp(as_[s0 * 4 + h] + adn);
        float4 v0 = *(const float4*)(xp + (size_t)s0 * FDIM + c);
        acc.x += w0 * v0.x; acc.y += w0 * v0.y;
        acc.z += w0 * v0.z; acc.w += w0 * v0.w;
        den += w0;
    }
    {   // self loop
        float w = leaky_exp(as_[n * 4 + h] + adn);
        float4 v = *(const float4*)(xp + (size_t)n * FDIM + c);
        acc.x += w * v.x; acc.y += w * v.y;
        acc.z += w * v.z; acc.w += w * v.w;
        den += w;
    }
    const float inv = 1.f / (den + 1e-16f);
    float4 b4 = *(const float4*)(bias + c);
    float o[4] = {acc.x * inv + b4.x, acc.y * inv + b4.y,
                  acc.z * inv + b4.z, acc.w * inv + b4.w};
#pragma unroll
    for (int j = 0; j < 4; ++j) o[j] = o[j] > 0.f ? o[j] : expf(o[j]) - 1.f;
    *(float4*)(out + (size_t)n * FDIM + c) = make_float4(o[0], o[1], o[2], o[3]);
}

// ---- layer-2 gather (H=1) fused with bias+ELU+BN+LN; wave per node ----
__global__ __launch_bounds__(256) void gather2_k(const float* __restrict__ xp,
                                                 const float* __restrict__ as_,
                                                 const float* __restrict__ ad_,
                                                 const int* __restrict__ rowptr,
                                                 const int* __restrict__ ssrc,
                                                 const float* __restrict__ bias,
                                                 const float* __restrict__ bng,
                                                 const float* __restrict__ bnb,
                                                 const float* __restrict__ bnm,
                                                 const float* __restrict__ bnv,
                                                 const float* __restrict__ lng,
                                                 const float* __restrict__ lnb,
                                                 float* __restrict__ out) {
    const int lane = threadIdx.x & 63;
    const int n = blockIdx.x * 4 + (threadIdx.x >> 6);
    if (n >= NNODES) return;
    const int c = lane << 2;
    const float adn = ad_[n];
    float4 acc = make_float4(0.f, 0.f, 0.f, 0.f);
    float den = 0.f;
    const int beg = rowptr[n], end = rowptr[n + 1];
    int e = beg;
    for (; e + 2 <= end; e += 2) {
        int s0 = ssrc[e], s1 = ssrc[e + 1];
        float a0 = as_[s0], a1 = as_[s1];
        float4 v0 = *(const float4*)(xp + (size_t)s0 * FDIM + c);
        float4 v1 = *(const float4*)(xp + (size_t)s1 * FDIM + c);
        float w0 = leaky_exp(a0 + adn), w1 = leaky_exp(a1 + adn);
        acc.x += w0 * v0.x + w1 * v1.x;
        acc.y += w0 * v0.y + w1 * v1.y;
        acc.z += w0 * v0.z + w1 * v1.z;
        acc.w += w0 * v0.w + w1 * v1.w;
        den += w0 + w1;
    }
    if (e < end) {
        int s0 = ssrc[e];
        float w0 = leaky_exp(as_[s0] + adn);
        float4 v0 = *(const float4*)(xp + (size_t)s0 * FDIM + c);
        acc.x += w0 * v0.x; acc.y += w0 * v0.y;
        acc.z += w0 * v0.z; acc.w += w0 * v0.w;
        den += w0;
    }
    {   // self loop
        float w = leaky_exp(as_[n] + adn);
        float4 v = *(const float4*)(xp + (size_t)n * FDIM + c);
        acc.x += w * v.x; acc.y += w * v.y;
        acc.z += w * v.z; acc.w += w * v.w;
        den += w;
    }
    const float inv = 1.f / (den + 1e-16f);
    float vals[4] = {acc.x * inv, acc.y * inv, acc.z * inv, acc.w * inv};
#pragma unroll
    for (int j = 0; j < 4; ++j) {
        float o = vals[j] + bias[c + j];
        o = o > 0.f ? o : expf(o) - 1.f;                               // ELU
        o = (o - bnm[c + j]) * rsqrtf(bnv[c + j] + 1e-5f) * bng[c + j]
            + bnb[c + j];                                              // BN (eval)
        vals[j] = o;
    }
    float s1 = vals[0] + vals[1] + vals[2] + vals[3];
    float s2 = vals[0] * vals[0] + vals[1] * vals[1] +
               vals[2] * vals[2] + vals[3] * vals[3];
#pragma unroll
    for (int off = 1; off < 64; off <<= 1) {
        s1 += __shfl_xor(s1, off);
        s2 += __shfl_xor(s2, off);
    }
    float mu  = s1 * (1.f / 256.f);
    float var = s2 * (1.f / 256.f) - mu * mu;
    float r   = rsqrtf(var + 1e-5f);
#pragma unroll
    for (int j = 0; j < 4; ++j)
        out[(size_t)n * FDIM + c + j] = (vals[j] - mu) * r * lng[c + j] + lnb[c + j];
}

extern "C" void kernel_launch(void* const* d_in, const int* in_sizes, int n_in,
                              void* d_out, int out_size, void* d_ws, size_t ws_size,
                              hipStream_t stream) {
    const float* x      = (const float*)d_in[0];
    const int*   ei     = (const int*)d_in[1];
    const float* W1     = (const float*)d_in[2];
    const float* atts1  = (const float*)d_in[3];
    const float* attd1  = (const float*)d_in[4];
    const float* bias1  = (const float*)d_in[5];
    const float* W2     = (const float*)d_in[6];
    const float* atts2  = (const float*)d_in[7];
    const float* attd2  = (const float*)d_in[8];
    const float* bias2  = (const float*)d_in[9];
    const float* bng    = (const float*)d_in[10];
    const float* bnb    = (const float*)d_in[11];
    const float* bnm    = (const float*)d_in[12];
    const float* bnv    = (const float*)d_in[13];
    const float* lng    = (const float*)d_in[14];
    const float* lnb    = (const float*)d_in[15];

    // ---- workspace layout ----
    float* xp   = (float*)d_ws;                        // N*256 f32 (51.2 MB)
    float* as1  = xp + (size_t)NNODES * FDIM;          // N*4
    float* ad1  = as1 + (size_t)NNODES * 4;            // N*4
    float* as2  = ad1 + (size_t)NNODES * 4;            // N
    float* ad2  = as2 + (size_t)NNODES;                // N
    int*   deg    = (int*)(ad2 + (size_t)NNODES);      // N
    int*   rowptr = deg + NNODES;                      // N+1
    int*   ssrc   = rowptr + (NNODES + 1);             // E
    float* hbuf = (float*)d_out;                       // h1 buffer / final output

    const dim3 gemm_grid((NNODES + 63) / 64, 4);
    const int node_wave_blocks = (NNODES + 3) / 4;
    const int edge_thread_blocks = (NEDGES + 255) / 256;

    // ---- CSR build (shared by both layers) ----
    hipMemsetAsync(deg, 0, NNODES * sizeof(int), stream);
    hist_k<<<edge_thread_blocks, 256, 0, stream>>>(ei, deg);
    scan_k<<<1, 1024, 0, stream>>>(deg, rowptr);
    scatter_k<<<edge_thread_blocks, 256, 0, stream>>>(ei, rowptr, deg, ssrc);

    // ---- layer 1 ----
    gemm256<<<gemm_grid, 256, 0, stream>>>(x, W1, xp, NNODES);
    aprep_k<4><<<node_wave_blocks, 256, 0, stream>>>(xp, atts1, attd1, as1, ad1);
    gather1_k<<<node_wave_blocks, 256, 0, stream>>>(xp, as1, ad1, rowptr, ssrc,
                                                    bias1, hbuf);

    // ---- layer 2 ----
    gemm256<<<gemm_grid, 256, 0, stream>>>(hbuf, W2, xp, NNODES);
    aprep_k<1><<<node_wave_blocks, 256, 0, stream>>>(xp, atts2, attd2, as2, ad2);
    gather2_k<<<node_wave_blocks, 256, 0, stream>>>(xp, as2, ad2, rowptr, ssrc,
                                                    bias2, bng, bnb, bnm, bnv,
                                                    lng, lnb, hbuf);
}

// Round 3
// 362.435 us; speedup vs baseline: 15.6406x; 1.7205x over previous
//
#include <hip/hip_runtime.h>
#include <cstddef>
#include <cstdint>

#define NNODES 50000
#define NEDGES 800000
#define FDIM   256

typedef __attribute__((ext_vector_type(8))) short short8;
typedef __attribute__((ext_vector_type(8))) unsigned short ushort8;
typedef __attribute__((ext_vector_type(4))) float f32x4;

__device__ __forceinline__ float leaky_exp(float a) {
    float e = a > 0.f ? a : 0.2f * a;
    return expf(e);
}
__device__ __forceinline__ unsigned short f2bf(float f) {
    uint32_t u = __builtin_bit_cast(uint32_t, f);
    u += 0x7fffu + ((u >> 16) & 1u);               // RNE
    return (unsigned short)(u >> 16);
}
__device__ __forceinline__ float bf2f(unsigned short h) {
    uint32_t u = ((uint32_t)h) << 16;
    return __builtin_bit_cast(float, u);
}

// ---------------- fp32 -> bf16 bulk convert (8 elems/thread) ----------------
__global__ __launch_bounds__(256) void cvt_k(const float* __restrict__ in,
                                             unsigned short* __restrict__ out,
                                             int n8) {
    int i = blockIdx.x * 256 + threadIdx.x;
    if (i >= n8) return;
    const float4* p = (const float4*)in + (size_t)i * 2;
    float4 a = p[0], b = p[1];
    ushort8 r;
    r[0] = f2bf(a.x); r[1] = f2bf(a.y); r[2] = f2bf(a.z); r[3] = f2bf(a.w);
    r[4] = f2bf(b.x); r[5] = f2bf(b.y); r[6] = f2bf(b.z); r[7] = f2bf(b.w);
    *(ushort8*)(out + (size_t)i * 8) = r;
}

// ------------- W[256][256] -> Wt[n][k] bf16 (transpose + convert) -------------
__global__ __launch_bounds__(256) void wprep_k(const float* __restrict__ W,
                                               unsigned short* __restrict__ Wt) {
    int n = blockIdx.x, k = threadIdx.x;
    Wt[n * 256 + k] = f2bf(W[k * 256 + n]);
}

// --------- bf16 MFMA GEMM: C[M,256] = A[M,256] @ Bt[256,256]^T, bf16 out ---------
// A row-major bf16, Bt = B transposed (row n holds k-contiguous), C bf16.
__global__ __launch_bounds__(256) void gemm_mfma(const unsigned short* __restrict__ A,
                                                 const unsigned short* __restrict__ Bt,
                                                 unsigned short* __restrict__ C, int M) {
    __shared__ unsigned short As[128 * 64];
    __shared__ unsigned short Bs[128 * 64];
    const int t = threadIdx.x;
    const int lane = t & 63, wid = t >> 6;
    const int wr = wid >> 1, wc = wid & 1;         // 2x2 waves, each 64x64 out
    const int bm = blockIdx.x * 128;
    const int bn = blockIdx.y * 128;
    f32x4 acc[4][4] = {};
    const int lrow = t >> 3, lslot = t & 7;        // staging: 32 rows x 8 slots per pass
    for (int k0 = 0; k0 < 256; k0 += 64) {
        __syncthreads();
#pragma unroll
        for (int i = 0; i < 4; ++i) {
            int row = lrow + 32 * i;
            int ga = bm + row; ga = ga < M ? ga : M - 1;
            uint4 av = *(const uint4*)(A + (size_t)ga * FDIM + k0 + lslot * 8);
            *(uint4*)(As + row * 64 + ((lslot ^ (row & 7)) << 3)) = av;   // T2 swizzle
            uint4 bv = *(const uint4*)(Bt + (size_t)(bn + row) * FDIM + k0 + lslot * 8);
            *(uint4*)(Bs + row * 64 + ((lslot ^ (row & 7)) << 3)) = bv;
        }
        __syncthreads();
#pragma unroll
        for (int ks = 0; ks < 2; ++ks) {
            const int kq = ks * 4 + (lane >> 4);   // 16B slot within row
            short8 a[4], b[4];
#pragma unroll
            for (int f = 0; f < 4; ++f) {
                int ra = wr * 64 + f * 16 + (lane & 15);
                a[f] = *(const short8*)(As + ra * 64 + ((kq ^ (ra & 7)) << 3));
                int rb = wc * 64 + f * 16 + (lane & 15);
                b[f] = *(const short8*)(Bs + rb * 64 + ((kq ^ (rb & 7)) << 3));
            }
#pragma unroll
            for (int mf = 0; mf < 4; ++mf)
#pragma unroll
                for (int nf = 0; nf < 4; ++nf)
                    acc[mf][nf] = __builtin_amdgcn_mfma_f32_16x16x32_bf16(
                        a[mf], b[nf], acc[mf][nf], 0, 0, 0);
        }
    }
    const int col0 = bn + wc * 64 + (lane & 15);
    const int row00 = bm + wr * 64 + (lane >> 4) * 4;   // C: col=lane&15, row=(lane>>4)*4+r
#pragma unroll
    for (int mf = 0; mf < 4; ++mf)
#pragma unroll
        for (int nf = 0; nf < 4; ++nf) {
            f32x4 v = acc[mf][nf];
            int col = col0 + nf * 16;
#pragma unroll
            for (int r = 0; r < 4; ++r) {
                int row = row00 + mf * 16 + r;
                if (row < M) C[(size_t)row * FDIM + col] = f2bf(v[r]);
            }
        }
}

// ------------- attention logits from bf16 xp; wave per node -------------
template <int H>
__global__ __launch_bounds__(256) void aprep_k(const unsigned short* __restrict__ xp,
                                               const float* __restrict__ atts,
                                               const float* __restrict__ attd,
                                               float* __restrict__ as_,
                                               float* __restrict__ ad_) {
    const int lane = threadIdx.x & 63;
    const int n = blockIdx.x * 4 + (threadIdx.x >> 6);
    if (n >= NNODES) return;
    const int c = lane << 2;
    ushort4 u = *(const ushort4*)(xp + (size_t)n * FDIM + c);
    float v0 = bf2f(u.x), v1 = bf2f(u.y), v2 = bf2f(u.z), v3 = bf2f(u.w);
    float4 s4 = *(const float4*)(atts + c);
    float4 d4 = *(const float4*)(attd + c);
    float ss = v0 * s4.x + v1 * s4.y + v2 * s4.z + v3 * s4.w;
    float sd = v0 * d4.x + v1 * d4.y + v2 * d4.z + v3 * d4.w;
    constexpr int G = 64 / H;
#pragma unroll
    for (int off = 1; off < G; off <<= 1) {
        ss += __shfl_xor(ss, off);
        sd += __shfl_xor(sd, off);
    }
    if ((lane & (G - 1)) == 0) {
        int h = lane / G;
        as_[n * H + h] = ss;
        ad_[n * H + h] = sd;
    }
}

// ---------------- CSR build: histogram -> scan -> scatter ----------------
__global__ __launch_bounds__(256) void hist_k(const int* __restrict__ ei,
                                              int* __restrict__ deg) {
    int e = blockIdx.x * 256 + threadIdx.x;
    if (e < NEDGES) atomicAdd(&deg[ei[NEDGES + e]], 1);
}

__global__ __launch_bounds__(1024) void scan_k(const int* __restrict__ deg,
                                               int* __restrict__ rowptr) {
    const int t = threadIdx.x;
    const int CHUNK = (NNODES + 1023) / 1024;
    const int lo = t * CHUNK;
    const int hi = min(lo + CHUNK, NNODES);
    int sum = 0;
    for (int i = lo; i < hi; ++i) sum += deg[i];
    const int lane = t & 63, wid = t >> 6;
    int v = sum;
#pragma unroll
    for (int off = 1; off < 64; off <<= 1) {
        int u = __shfl_up(v, off);
        if (lane >= off) v += u;
    }
    __shared__ int wsum[16], woff[16];
    if (lane == 63) wsum[wid] = v;
    __syncthreads();
    if (t == 0) {
        int acc = 0;
        for (int i = 0; i < 16; ++i) { woff[i] = acc; acc += wsum[i]; }
        rowptr[NNODES] = acc;
    }
    __syncthreads();
    int excl = woff[wid] + (v - sum);
    for (int i = lo; i < hi; ++i) { rowptr[i] = excl; excl += deg[i]; }
}

__global__ __launch_bounds__(256) void scatter_k(const int* __restrict__ ei,
                                                 const int* __restrict__ rowptr,
                                                 int* __restrict__ deg,
                                                 int* __restrict__ ssrc) {
    int e = blockIdx.x * 256 + threadIdx.x;
    if (e >= NEDGES) return;
    int s = ei[e], d = ei[NEDGES + e];
    int old = atomicSub(&deg[d], 1);
    ssrc[rowptr[d + 1] - old] = s;
}

// ---- layer-1 gather (H=4): wave per node, bf16 rows, bias+ELU, bf16 out ----
__global__ __launch_bounds__(256) void gather1_k(const unsigned short* __restrict__ xp,
                                                 const float* __restrict__ as_,
                                                 const float* __restrict__ ad_,
                                                 const int* __restrict__ rowptr,
                                                 const int* __restrict__ ssrc,
                                                 const float* __restrict__ bias,
                                                 unsigned short* __restrict__ out) {
    const int lane = threadIdx.x & 63;
    const int n = blockIdx.x * 4 + (threadIdx.x >> 6);
    if (n >= NNODES) return;
    const int h = lane >> 4;
    const int c = lane << 2;
    const float adn = ad_[n * 4 + h];
    float ax = 0.f, ay = 0.f, az = 0.f, aw = 0.f, den = 0.f;
    const int beg = rowptr[n], end = rowptr[n + 1];
    int e = beg;
    for (; e + 4 <= end; e += 4) {
        int s0 = ssrc[e], s1 = ssrc[e + 1], s2 = ssrc[e + 2], s3 = ssrc[e + 3];
        float w0 = leaky_exp(as_[s0 * 4 + h] + adn);
        float w1 = leaky_exp(as_[s1 * 4 + h] + adn);
        float w2 = leaky_exp(as_[s2 * 4 + h] + adn);
        float w3 = leaky_exp(as_[s3 * 4 + h] + adn);
        ushort4 u0 = *(const ushort4*)(xp + (size_t)s0 * FDIM + c);
        ushort4 u1 = *(const ushort4*)(xp + (size_t)s1 * FDIM + c);
        ushort4 u2 = *(const ushort4*)(xp + (size_t)s2 * FDIM + c);
        ushort4 u3 = *(const ushort4*)(xp + (size_t)s3 * FDIM + c);
        ax += w0 * bf2f(u0.x) + w1 * bf2f(u1.x) + w2 * bf2f(u2.x) + w3 * bf2f(u3.x);
        ay += w0 * bf2f(u0.y) + w1 * bf2f(u1.y) + w2 * bf2f(u2.y) + w3 * bf2f(u3.y);
        az += w0 * bf2f(u0.z) + w1 * bf2f(u1.z) + w2 * bf2f(u2.z) + w3 * bf2f(u3.z);
        aw += w0 * bf2f(u0.w) + w1 * bf2f(u1.w) + w2 * bf2f(u2.w) + w3 * bf2f(u3.w);
        den += (w0 + w1) + (w2 + w3);
    }
    for (; e < end; ++e) {
        int s0 = ssrc[e];
        float w0 = leaky_exp(as_[s0 * 4 + h] + adn);
        ushort4 u0 = *(const ushort4*)(xp + (size_t)s0 * FDIM + c);
        ax += w0 * bf2f(u0.x); ay += w0 * bf2f(u0.y);
        az += w0 * bf2f(u0.z); aw += w0 * bf2f(u0.w);
        den += w0;
    }
    {   // self loop
        float w = leaky_exp(as_[n * 4 + h] + adn);
        ushort4 u = *(const ushort4*)(xp + (size_t)n * FDIM + c);
        ax += w * bf2f(u.x); ay += w * bf2f(u.y);
        az += w * bf2f(u.z); aw += w * bf2f(u.w);
        den += w;
    }
    const float inv = 1.f / (den + 1e-16f);
    float4 b4 = *(const float4*)(bias + c);
    float o[4] = {ax * inv + b4.x, ay * inv + b4.y,
                  az * inv + b4.z, aw * inv + b4.w};
#pragma unroll
    for (int j = 0; j < 4; ++j) o[j] = o[j] > 0.f ? o[j] : expf(o[j]) - 1.f;
    ushort4 r;
    r.x = f2bf(o[0]); r.y = f2bf(o[1]); r.z = f2bf(o[2]); r.w = f2bf(o[3]);
    *(ushort4*)(out + (size_t)n * FDIM + c) = r;
}

// ---- layer-2 gather (H=1) + bias+ELU+BN+LN; wave per node; fp32 out ----
__global__ __launch_bounds__(256) void gather2_k(const unsigned short* __restrict__ xp,
                                                 const float* __restrict__ as_,
                                                 const float* __restrict__ ad_,
                                                 const int* __restrict__ rowptr,
                                                 const int* __restrict__ ssrc,
                                                 const float* __restrict__ bias,
                                                 const float* __restrict__ bng,
                                                 const float* __restrict__ bnb,
                                                 const float* __restrict__ bnm,
                                                 const float* __restrict__ bnv,
                                                 const float* __restrict__ lng,
                                                 const float* __restrict__ lnb,
                                                 float* __restrict__ out) {
    const int lane = threadIdx.x & 63;
    const int n = blockIdx.x * 4 + (threadIdx.x >> 6);
    if (n >= NNODES) return;
    const int c = lane << 2;
    const float adn = ad_[n];
    float ax = 0.f, ay = 0.f, az = 0.f, aw = 0.f, den = 0.f;
    const int beg = rowptr[n], end = rowptr[n + 1];
    int e = beg;
    for (; e + 4 <= end; e += 4) {
        int s0 = ssrc[e], s1 = ssrc[e + 1], s2 = ssrc[e + 2], s3 = ssrc[e + 3];
        float w0 = leaky_exp(as_[s0] + adn);
        float w1 = leaky_exp(as_[s1] + adn);
        float w2 = leaky_exp(as_[s2] + adn);
        float w3 = leaky_exp(as_[s3] + adn);
        ushort4 u0 = *(const ushort4*)(xp + (size_t)s0 * FDIM + c);
        ushort4 u1 = *(const ushort4*)(xp + (size_t)s1 * FDIM + c);
        ushort4 u2 = *(const ushort4*)(xp + (size_t)s2 * FDIM + c);
        ushort4 u3 = *(const ushort4*)(xp + (size_t)s3 * FDIM + c);
        ax += w0 * bf2f(u0.x) + w1 * bf2f(u1.x) + w2 * bf2f(u2.x) + w3 * bf2f(u3.x);
        ay += w0 * bf2f(u0.y) + w1 * bf2f(u1.y) + w2 * bf2f(u2.y) + w3 * bf2f(u3.y);
        az += w0 * bf2f(u0.z) + w1 * bf2f(u1.z) + w2 * bf2f(u2.z) + w3 * bf2f(u3.z);
        aw += w0 * bf2f(u0.w) + w1 * bf2f(u1.w) + w2 * bf2f(u2.w) + w3 * bf2f(u3.w);
        den += (w0 + w1) + (w2 + w3);
    }
    for (; e < end; ++e) {
        int s0 = ssrc[e];
        float w0 = leaky_exp(as_[s0] + adn);
        ushort4 u0 = *(const ushort4*)(xp + (size_t)s0 * FDIM + c);
        ax += w0 * bf2f(u0.x); ay += w0 * bf2f(u0.y);
        az += w0 * bf2f(u0.z); aw += w0 * bf2f(u0.w);
        den += w0;
    }
    {   // self loop
        float w = leaky_exp(as_[n] + adn);
        ushort4 u = *(const ushort4*)(xp + (size_t)n * FDIM + c);
        ax += w * bf2f(u.x); ay += w * bf2f(u.y);
        az += w * bf2f(u.z); aw += w * bf2f(u.w);
        den += w;
    }
    const float inv = 1.f / (den + 1e-16f);
    float vals[4] = {ax * inv, ay * inv, az * inv, aw * inv};
#pragma unroll
    for (int j = 0; j < 4; ++j) {
        float o = vals[j] + bias[c + j];
        o = o > 0.f ? o : expf(o) - 1.f;                               // ELU
        o = (o - bnm[c + j]) * rsqrtf(bnv[c + j] + 1e-5f) * bng[c + j]
            + bnb[c + j];                                              // BN
        vals[j] = o;
    }
    float s1 = vals[0] + vals[1] + vals[2] + vals[3];
    float s2 = vals[0] * vals[0] + vals[1] * vals[1] +
               vals[2] * vals[2] + vals[3] * vals[3];
#pragma unroll
    for (int off = 1; off < 64; off <<= 1) {
        s1 += __shfl_xor(s1, off);
        s2 += __shfl_xor(s2, off);
    }
    float mu  = s1 * (1.f / 256.f);
    float var = s2 * (1.f / 256.f) - mu * mu;
    float r   = rsqrtf(var + 1e-5f);
#pragma unroll
    for (int j = 0; j < 4; ++j)
        out[(size_t)n * FDIM + c + j] = (vals[j] - mu) * r * lng[c + j] + lnb[c + j];
}

extern "C" void kernel_launch(void* const* d_in, const int* in_sizes, int n_in,
                              void* d_out, int out_size, void* d_ws, size_t ws_size,
                              hipStream_t stream) {
    const float* x      = (const float*)d_in[0];
    const int*   ei     = (const int*)d_in[1];
    const float* W1     = (const float*)d_in[2];
    const float* atts1  = (const float*)d_in[3];
    const float* attd1  = (const float*)d_in[4];
    const float* bias1  = (const float*)d_in[5];
    const float* W2     = (const float*)d_in[6];
    const float* atts2  = (const float*)d_in[7];
    const float* attd2  = (const float*)d_in[8];
    const float* bias2  = (const float*)d_in[9];
    const float* bng    = (const float*)d_in[10];
    const float* bnb    = (const float*)d_in[11];
    const float* bnm    = (const float*)d_in[12];
    const float* bnv    = (const float*)d_in[13];
    const float* lng    = (const float*)d_in[14];
    const float* lnb    = (const float*)d_in[15];

    const size_t NF = (size_t)NNODES * FDIM;          // 12.8M elems
    unsigned short* xpbf = (unsigned short*)d_ws;     // 25.6 MB (xp both layers)
    unsigned short* xbf  = xpbf + NF;                 // 25.6 MB (x bf16, then h1 bf16)
    unsigned short* wt1  = xbf + NF;                  // 128 KB
    unsigned short* wt2  = wt1 + 65536;               // 128 KB
    float* as1   = (float*)(wt2 + 65536);             // N*4
    float* ad1   = as1 + (size_t)NNODES * 4;          // N*4
    float* as2   = ad1 + (size_t)NNODES * 4;          // N
    float* ad2   = as2 + NNODES;                      // N
    int*   deg    = (int*)(ad2 + NNODES);             // N
    int*   rowptr = deg + NNODES;                     // N+1
    int*   ssrc   = rowptr + (NNODES + 1);            // E
    float* outf  = (float*)d_out;

    const dim3 gemm_grid((NNODES + 127) / 128, 2);
    const int node_wave_blocks = (NNODES + 3) / 4;
    const int edge_thread_blocks = (NEDGES + 255) / 256;
    const int cvt_blocks = (int)((NF / 8 + 255) / 256);

    // ---- prep: conversions + CSR (graph shared by both layers) ----
    cvt_k<<<cvt_blocks, 256, 0, stream>>>(x, xbf, (int)(NF / 8));
    wprep_k<<<256, 256, 0, stream>>>(W1, wt1);
    wprep_k<<<256, 256, 0, stream>>>(W2, wt2);
    hipMemsetAsync(deg, 0, NNODES * sizeof(int), stream);
    hist_k<<<edge_thread_blocks, 256, 0, stream>>>(ei, deg);
    scan_k<<<1, 1024, 0, stream>>>(deg, rowptr);
    scatter_k<<<edge_thread_blocks, 256, 0, stream>>>(ei, rowptr, deg, ssrc);

    // ---- layer 1 ----
    gemm_mfma<<<gemm_grid, 256, 0, stream>>>(xbf, wt1, xpbf, NNODES);
    aprep_k<4><<<node_wave_blocks, 256, 0, stream>>>(xpbf, atts1, attd1, as1, ad1);
    gather1_k<<<node_wave_blocks, 256, 0, stream>>>(xpbf, as1, ad1, rowptr, ssrc,
                                                    bias1, xbf /* h1 bf16 */);

    // ---- layer 2 ----
    gemm_mfma<<<gemm_grid, 256, 0, stream>>>(xbf, wt2, xpbf, NNODES);
    aprep_k<1><<<node_wave_blocks, 256, 0, stream>>>(xpbf, atts2, attd2, as2, ad2);
    gather2_k<<<node_wave_blocks, 256, 0, stream>>>(xpbf, as2, ad2, rowptr, ssrc,
                                                    bias2, bng, bnb, bnm, bnv,
                                                    lng, lnb, outf);
}

// Round 4
// 360.697 us; speedup vs baseline: 15.7160x; 1.0048x over previous
//
#include <hip/hip_runtime.h>
#include <cstddef>
#include <cstdint>

#define NNODES 50000
#define NEDGES 800000
#define FDIM   256

typedef __attribute__((ext_vector_type(8))) short short8;
typedef __attribute__((ext_vector_type(8))) unsigned short ushort8;
typedef __attribute__((ext_vector_type(4))) float f32x4;

__device__ __forceinline__ float leaky_exp(float a) {
    float e = a > 0.f ? a : 0.2f * a;
    return __expf(e);
}
__device__ __forceinline__ unsigned short f2bf(float f) {
    uint32_t u = __builtin_bit_cast(uint32_t, f);
    u += 0x7fffu + ((u >> 16) & 1u);               // RNE
    return (unsigned short)(u >> 16);
}
__device__ __forceinline__ float bf2f(unsigned short h) {
    uint32_t u = ((uint32_t)h) << 16;
    return __builtin_bit_cast(float, u);
}
__device__ __forceinline__ float bflo(uint32_t u) {
    return __builtin_bit_cast(float, u << 16);
}
__device__ __forceinline__ float bfhi(uint32_t u) {
    return __builtin_bit_cast(float, u & 0xffff0000u);
}
__device__ __forceinline__ float rlanef(float v, int l) {
    return __builtin_bit_cast(float,
        __builtin_amdgcn_readlane(__builtin_bit_cast(int, v), l));
}

// ---------------- fp32 -> bf16 bulk convert (8 elems/thread) ----------------
__global__ __launch_bounds__(256) void cvt_k(const float* __restrict__ in,
                                             unsigned short* __restrict__ out,
                                             int n8) {
    int i = blockIdx.x * 256 + threadIdx.x;
    if (i >= n8) return;
    const float4* p = (const float4*)in + (size_t)i * 2;
    float4 a = p[0], b = p[1];
    ushort8 r;
    r[0] = f2bf(a.x); r[1] = f2bf(a.y); r[2] = f2bf(a.z); r[3] = f2bf(a.w);
    r[4] = f2bf(b.x); r[5] = f2bf(b.y); r[6] = f2bf(b.z); r[7] = f2bf(b.w);
    *(ushort8*)(out + (size_t)i * 8) = r;
}

// ------------- W[256][256] -> Wt[n][k] bf16 (transpose + convert) -------------
__global__ __launch_bounds__(256) void wprep_k(const float* __restrict__ W,
                                               unsigned short* __restrict__ Wt) {
    int n = blockIdx.x, k = threadIdx.x;
    Wt[n * 256 + k] = f2bf(W[k * 256 + n]);
}

// --------- bf16 MFMA GEMM: C[M,256] = A[M,256] @ Bt[256,256]^T, bf16 out ---------
__global__ __launch_bounds__(256) void gemm_mfma(const unsigned short* __restrict__ A,
                                                 const unsigned short* __restrict__ Bt,
                                                 unsigned short* __restrict__ C, int M) {
    __shared__ unsigned short As[128 * 64];
    __shared__ unsigned short Bs[128 * 64];
    const int t = threadIdx.x;
    const int lane = t & 63, wid = t >> 6;
    const int wr = wid >> 1, wc = wid & 1;
    const int bm = blockIdx.x * 128;
    const int bn = blockIdx.y * 128;
    f32x4 acc[4][4] = {};
    const int lrow = t >> 3, lslot = t & 7;
    for (int k0 = 0; k0 < 256; k0 += 64) {
        __syncthreads();
#pragma unroll
        for (int i = 0; i < 4; ++i) {
            int row = lrow + 32 * i;
            int ga = bm + row; ga = ga < M ? ga : M - 1;
            uint4 av = *(const uint4*)(A + (size_t)ga * FDIM + k0 + lslot * 8);
            *(uint4*)(As + row * 64 + ((lslot ^ (row & 7)) << 3)) = av;
            uint4 bv = *(const uint4*)(Bt + (size_t)(bn + row) * FDIM + k0 + lslot * 8);
            *(uint4*)(Bs + row * 64 + ((lslot ^ (row & 7)) << 3)) = bv;
        }
        __syncthreads();
#pragma unroll
        for (int ks = 0; ks < 2; ++ks) {
            const int kq = ks * 4 + (lane >> 4);
            short8 a[4], b[4];
#pragma unroll
            for (int f = 0; f < 4; ++f) {
                int ra = wr * 64 + f * 16 + (lane & 15);
                a[f] = *(const short8*)(As + ra * 64 + ((kq ^ (ra & 7)) << 3));
                int rb = wc * 64 + f * 16 + (lane & 15);
                b[f] = *(const short8*)(Bs + rb * 64 + ((kq ^ (rb & 7)) << 3));
            }
#pragma unroll
            for (int mf = 0; mf < 4; ++mf)
#pragma unroll
                for (int nf = 0; nf < 4; ++nf)
                    acc[mf][nf] = __builtin_amdgcn_mfma_f32_16x16x32_bf16(
                        a[mf], b[nf], acc[mf][nf], 0, 0, 0);
        }
    }
    const int col0 = bn + wc * 64 + (lane & 15);
    const int row00 = bm + wr * 64 + (lane >> 4) * 4;
#pragma unroll
    for (int mf = 0; mf < 4; ++mf)
#pragma unroll
        for (int nf = 0; nf < 4; ++nf) {
            f32x4 v = acc[mf][nf];
            int col = col0 + nf * 16;
#pragma unroll
            for (int r = 0; r < 4; ++r) {
                int row = row00 + mf * 16 + r;
                if (row < M) C[(size_t)row * FDIM + col] = f2bf(v[r]);
            }
        }
}

// ------------- attention logits from bf16 xp; wave per node -------------
template <int H>
__global__ __launch_bounds__(256) void aprep_k(const unsigned short* __restrict__ xp,
                                               const float* __restrict__ atts,
                                               const float* __restrict__ attd,
                                               float* __restrict__ as_,
                                               float* __restrict__ ad_) {
    const int lane = threadIdx.x & 63;
    const int n = blockIdx.x * 4 + (threadIdx.x >> 6);
    if (n >= NNODES) return;
    const int c = lane << 2;
    ushort4 u = *(const ushort4*)(xp + (size_t)n * FDIM + c);
    float v0 = bf2f(u.x), v1 = bf2f(u.y), v2 = bf2f(u.z), v3 = bf2f(u.w);
    float4 s4 = *(const float4*)(atts + c);
    float4 d4 = *(const float4*)(attd + c);
    float ss = v0 * s4.x + v1 * s4.y + v2 * s4.z + v3 * s4.w;
    float sd = v0 * d4.x + v1 * d4.y + v2 * d4.z + v3 * d4.w;
    constexpr int G = 64 / H;
#pragma unroll
    for (int off = 1; off < G; off <<= 1) {
        ss += __shfl_xor(ss, off);
        sd += __shfl_xor(sd, off);
    }
    if ((lane & (G - 1)) == 0) {
        int h = lane / G;
        as_[n * H + h] = ss;
        ad_[n * H + h] = sd;
    }
}

// ---------------- CSR build: histogram -> scan -> scatter ----------------
__global__ __launch_bounds__(256) void hist_k(const int* __restrict__ ei,
                                              int* __restrict__ deg) {
    int e = blockIdx.x * 256 + threadIdx.x;
    if (e < NEDGES) atomicAdd(&deg[ei[NEDGES + e]], 1);
}

__global__ __launch_bounds__(1024) void scan_k(const int* __restrict__ deg,
                                               int* __restrict__ rowptr) {
    const int t = threadIdx.x;
    const int CHUNK = (NNODES + 1023) / 1024;
    const int lo = t * CHUNK;
    const int hi = min(lo + CHUNK, NNODES);
    int sum = 0;
    for (int i = lo; i < hi; ++i) sum += deg[i];
    const int lane = t & 63, wid = t >> 6;
    int v = sum;
#pragma unroll
    for (int off = 1; off < 64; off <<= 1) {
        int u = __shfl_up(v, off);
        if (lane >= off) v += u;
    }
    __shared__ int wsum[16], woff[16];
    if (lane == 63) wsum[wid] = v;
    __syncthreads();
    if (t == 0) {
        int acc = 0;
        for (int i = 0; i < 16; ++i) { woff[i] = acc; acc += wsum[i]; }
        rowptr[NNODES] = acc;
    }
    __syncthreads();
    int excl = woff[wid] + (v - sum);
    for (int i = lo; i < hi; ++i) { rowptr[i] = excl; excl += deg[i]; }
}

__global__ __launch_bounds__(256) void scatter_k(const int* __restrict__ ei,
                                                 const int* __restrict__ rowptr,
                                                 int* __restrict__ deg,
                                                 int* __restrict__ ssrc) {
    int e = blockIdx.x * 256 + threadIdx.x;
    if (e >= NEDGES) return;
    int s = ei[e], d = ei[NEDGES + e];
    int old = atomicSub(&deg[d], 1);
    ssrc[rowptr[d + 1] - old] = s;
}

// ---- layer-1 gather (H=4): strip-mined weights + shfl broadcast ----
__global__ __launch_bounds__(256) void gather1_k(const unsigned short* __restrict__ xp,
                                                 const float* __restrict__ as_,
                                                 const float* __restrict__ ad_,
                                                 const int* __restrict__ rowptr,
                                                 const int* __restrict__ ssrc,
                                                 const float* __restrict__ bias,
                                                 unsigned short* __restrict__ out) {
    const int lane = threadIdx.x & 63;
    const int n = blockIdx.x * 4 + (threadIdx.x >> 6);
    if (n >= NNODES) return;
    const int h = lane >> 4;            // head for feature lanes
    const int c = lane << 2;
    const int eloc = lane >> 2;         // strip edge slot (0..15)
    const int hh = lane & 3;            // strip head slot
    const float adW = ad_[n * 4 + hh];  // for weight phase
    float a0 = 0.f, a1 = 0.f, a2 = 0.f, a3 = 0.f, den = 0.f;
    const int beg = rowptr[n], end = rowptr[n + 1];
    for (int base = beg; base < end; base += 16) {
        int my_e = base + eloc;
        float wv = 0.f; int sv = 0;
        if (my_e < end) {
            sv = ssrc[my_e];
            wv = leaky_exp(as_[sv * 4 + hh] + adW);
        }
        const int cnt = min(16, end - base);
        int e = 0;
        for (; e + 4 <= cnt; e += 4) {
#pragma unroll
            for (int q = 0; q < 4; ++q) {
                // hoist the 4 row loads ahead of use via grouped issue
            }
            int s0 = __builtin_amdgcn_readlane(sv, (e + 0) << 2);
            int s1 = __builtin_amdgcn_readlane(sv, (e + 1) << 2);
            int s2 = __builtin_amdgcn_readlane(sv, (e + 2) << 2);
            int s3 = __builtin_amdgcn_readlane(sv, (e + 3) << 2);
            uint2 u0 = *(const uint2*)(xp + (((unsigned)s0 << 8) + (unsigned)c));
            uint2 u1 = *(const uint2*)(xp + (((unsigned)s1 << 8) + (unsigned)c));
            uint2 u2 = *(const uint2*)(xp + (((unsigned)s2 << 8) + (unsigned)c));
            uint2 u3 = *(const uint2*)(xp + (((unsigned)s3 << 8) + (unsigned)c));
            float w0 = __shfl(wv, ((e + 0) << 2) | h);
            float w1 = __shfl(wv, ((e + 1) << 2) | h);
            float w2 = __shfl(wv, ((e + 2) << 2) | h);
            float w3 = __shfl(wv, ((e + 3) << 2) | h);
            a0 += w0 * bflo(u0.x) + w1 * bflo(u1.x) + w2 * bflo(u2.x) + w3 * bflo(u3.x);
            a1 += w0 * bfhi(u0.x) + w1 * bfhi(u1.x) + w2 * bfhi(u2.x) + w3 * bfhi(u3.x);
            a2 += w0 * bflo(u0.y) + w1 * bflo(u1.y) + w2 * bflo(u2.y) + w3 * bflo(u3.y);
            a3 += w0 * bfhi(u0.y) + w1 * bfhi(u1.y) + w2 * bfhi(u2.y) + w3 * bfhi(u3.y);
            den += (w0 + w1) + (w2 + w3);
        }
        for (; e < cnt; ++e) {
            int s0 = __builtin_amdgcn_readlane(sv, e << 2);
            uint2 u0 = *(const uint2*)(xp + (((unsigned)s0 << 8) + (unsigned)c));
            float w0 = __shfl(wv, (e << 2) | h);
            a0 += w0 * bflo(u0.x); a1 += w0 * bfhi(u0.x);
            a2 += w0 * bflo(u0.y); a3 += w0 * bfhi(u0.y);
            den += w0;
        }
    }
    {   // self loop
        float w = leaky_exp(as_[n * 4 + h] + ad_[n * 4 + h]);
        uint2 u = *(const uint2*)(xp + (((unsigned)n << 8) + (unsigned)c));
        a0 += w * bflo(u.x); a1 += w * bfhi(u.x);
        a2 += w * bflo(u.y); a3 += w * bfhi(u.y);
        den += w;
    }
    const float inv = 1.f / (den + 1e-16f);
    float4 b4 = *(const float4*)(bias + c);
    float o[4] = {a0 * inv + b4.x, a1 * inv + b4.y,
                  a2 * inv + b4.z, a3 * inv + b4.w};
#pragma unroll
    for (int j = 0; j < 4; ++j) o[j] = o[j] > 0.f ? o[j] : __expf(o[j]) - 1.f;
    ushort4 r;
    r.x = f2bf(o[0]); r.y = f2bf(o[1]); r.z = f2bf(o[2]); r.w = f2bf(o[3]);
    *(ushort4*)(out + (size_t)n * FDIM + c) = r;
}

// ---- layer-2 gather (H=1): 64-edge strips, SGPR weight broadcast; +BN+LN ----
__global__ __launch_bounds__(256) void gather2_k(const unsigned short* __restrict__ xp,
                                                 const float* __restrict__ as_,
                                                 const float* __restrict__ ad_,
                                                 const int* __restrict__ rowptr,
                                                 const int* __restrict__ ssrc,
                                                 const float* __restrict__ bias,
                                                 const float* __restrict__ bng,
                                                 const float* __restrict__ bnb,
                                                 const float* __restrict__ bnm,
                                                 const float* __restrict__ bnv,
                                                 const float* __restrict__ lng,
                                                 const float* __restrict__ lnb,
                                                 float* __restrict__ out) {
    const int lane = threadIdx.x & 63;
    const int n = blockIdx.x * 4 + (threadIdx.x >> 6);
    if (n >= NNODES) return;
    const int c = lane << 2;
    const float adn = ad_[n];
    float a0 = 0.f, a1 = 0.f, a2 = 0.f, a3 = 0.f, den = 0.f;
    const int beg = rowptr[n], end = rowptr[n + 1];
    for (int base = beg; base < end; base += 64) {
        int my_e = base + lane;
        float wv = 0.f; int sv = 0;
        if (my_e < end) {
            sv = ssrc[my_e];
            wv = leaky_exp(as_[sv] + adn);
        }
        const int cnt = min(64, end - base);
        int e = 0;
        for (; e + 4 <= cnt; e += 4) {
            int s0 = __builtin_amdgcn_readlane(sv, e + 0);
            int s1 = __builtin_amdgcn_readlane(sv, e + 1);
            int s2 = __builtin_amdgcn_readlane(sv, e + 2);
            int s3 = __builtin_amdgcn_readlane(sv, e + 3);
            uint2 u0 = *(const uint2*)(xp + (((unsigned)s0 << 8) + (unsigned)c));
            uint2 u1 = *(const uint2*)(xp + (((unsigned)s1 << 8) + (unsigned)c));
            uint2 u2 = *(const uint2*)(xp + (((unsigned)s2 << 8) + (unsigned)c));
            uint2 u3 = *(const uint2*)(xp + (((unsigned)s3 << 8) + (unsigned)c));
            float w0 = rlanef(wv, e + 0);
            float w1 = rlanef(wv, e + 1);
            float w2 = rlanef(wv, e + 2);
            float w3 = rlanef(wv, e + 3);
            a0 += w0 * bflo(u0.x) + w1 * bflo(u1.x) + w2 * bflo(u2.x) + w3 * bflo(u3.x);
            a1 += w0 * bfhi(u0.x) + w1 * bfhi(u1.x) + w2 * bfhi(u2.x) + w3 * bfhi(u3.x);
            a2 += w0 * bflo(u0.y) + w1 * bflo(u1.y) + w2 * bflo(u2.y) + w3 * bflo(u3.y);
            a3 += w0 * bfhi(u0.y) + w1 * bfhi(u1.y) + w2 * bfhi(u2.y) + w3 * bfhi(u3.y);
            den += (w0 + w1) + (w2 + w3);
        }
        for (; e < cnt; ++e) {
            int s0 = __builtin_amdgcn_readlane(sv, e);
            uint2 u0 = *(const uint2*)(xp + (((unsigned)s0 << 8) + (unsigned)c));
            float w0 = rlanef(wv, e);
            a0 += w0 * bflo(u0.x); a1 += w0 * bfhi(u0.x);
            a2 += w0 * bflo(u0.y); a3 += w0 * bfhi(u0.y);
            den += w0;
        }
    }
    {   // self loop
        float w = leaky_exp(as_[n] + adn);
        uint2 u = *(const uint2*)(xp + (((unsigned)n << 8) + (unsigned)c));
        a0 += w * bflo(u.x); a1 += w * bfhi(u.x);
        a2 += w * bflo(u.y); a3 += w * bfhi(u.y);
        den += w;
    }
    const float inv = 1.f / (den + 1e-16f);
    float vals[4] = {a0 * inv, a1 * inv, a2 * inv, a3 * inv};
#pragma unroll
    for (int j = 0; j < 4; ++j) {
        float o = vals[j] + bias[c + j];
        o = o > 0.f ? o : __expf(o) - 1.f;                             // ELU
        o = (o - bnm[c + j]) * rsqrtf(bnv[c + j] + 1e-5f) * bng[c + j]
            + bnb[c + j];                                              // BN
        vals[j] = o;
    }
    float s1 = vals[0] + vals[1] + vals[2] + vals[3];
    float s2 = vals[0] * vals[0] + vals[1] * vals[1] +
               vals[2] * vals[2] + vals[3] * vals[3];
#pragma unroll
    for (int off = 1; off < 64; off <<= 1) {
        s1 += __shfl_xor(s1, off);
        s2 += __shfl_xor(s2, off);
    }
    float mu  = s1 * (1.f / 256.f);
    float var = s2 * (1.f / 256.f) - mu * mu;
    float r   = rsqrtf(var + 1e-5f);
#pragma unroll
    for (int j = 0; j < 4; ++j)
        out[(size_t)n * FDIM + c + j] = (vals[j] - mu) * r * lng[c + j] + lnb[c + j];
}

extern "C" void kernel_launch(void* const* d_in, const int* in_sizes, int n_in,
                              void* d_out, int out_size, void* d_ws, size_t ws_size,
                              hipStream_t stream) {
    const float* x      = (const float*)d_in[0];
    const int*   ei     = (const int*)d_in[1];
    const float* W1     = (const float*)d_in[2];
    const float* atts1  = (const float*)d_in[3];
    const float* attd1  = (const float*)d_in[4];
    const float* bias1  = (const float*)d_in[5];
    const float* W2     = (const float*)d_in[6];
    const float* atts2  = (const float*)d_in[7];
    const float* attd2  = (const float*)d_in[8];
    const float* bias2  = (const float*)d_in[9];
    const float* bng    = (const float*)d_in[10];
    const float* bnb    = (const float*)d_in[11];
    const float* bnm    = (const float*)d_in[12];
    const float* bnv    = (const float*)d_in[13];
    const float* lng    = (const float*)d_in[14];
    const float* lnb    = (const float*)d_in[15];

    const size_t NF = (size_t)NNODES * FDIM;
    unsigned short* xpbf = (unsigned short*)d_ws;     // 25.6 MB
    unsigned short* xbf  = xpbf + NF;                 // 25.6 MB (x bf16, then h1)
    unsigned short* wt1  = xbf + NF;
    unsigned short* wt2  = wt1 + 65536;
    float* as1   = (float*)(wt2 + 65536);
    float* ad1   = as1 + (size_t)NNODES * 4;
    float* as2   = ad1 + (size_t)NNODES * 4;
    float* ad2   = as2 + NNODES;
    int*   deg    = (int*)(ad2 + NNODES);
    int*   rowptr = deg + NNODES;
    int*   ssrc   = rowptr + (NNODES + 1);
    float* outf  = (float*)d_out;

    const dim3 gemm_grid((NNODES + 127) / 128, 2);
    const int node_wave_blocks = (NNODES + 3) / 4;
    const int edge_thread_blocks = (NEDGES + 255) / 256;
    const int cvt_blocks = (int)((NF / 8 + 255) / 256);

    // ---- prep: conversions + CSR ----
    cvt_k<<<cvt_blocks, 256, 0, stream>>>(x, xbf, (int)(NF / 8));
    wprep_k<<<256, 256, 0, stream>>>(W1, wt1);
    wprep_k<<<256, 256, 0, stream>>>(W2, wt2);
    hipMemsetAsync(deg, 0, NNODES * sizeof(int), stream);
    hist_k<<<edge_thread_blocks, 256, 0, stream>>>(ei, deg);
    scan_k<<<1, 1024, 0, stream>>>(deg, rowptr);
    scatter_k<<<edge_thread_blocks, 256, 0, stream>>>(ei, rowptr, deg, ssrc);

    // ---- layer 1 ----
    gemm_mfma<<<gemm_grid, 256, 0, stream>>>(xbf, wt1, xpbf, NNODES);
    aprep_k<4><<<node_wave_blocks, 256, 0, stream>>>(xpbf, atts1, attd1, as1, ad1);
    gather1_k<<<node_wave_blocks, 256, 0, stream>>>(xpbf, as1, ad1, rowptr, ssrc,
                                                    bias1, xbf);

    // ---- layer 2 ----
    gemm_mfma<<<gemm_grid, 256, 0, stream>>>(xbf, wt2, xpbf, NNODES);
    aprep_k<1><<<node_wave_blocks, 256, 0, stream>>>(xpbf, atts2, attd2, as2, ad2);
    gather2_k<<<node_wave_blocks, 256, 0, stream>>>(xpbf, as2, ad2, rowptr, ssrc,
                                                    bias2, bng, bnb, bnm, bnv,
                                                    lng, lnb, outf);
}

// Round 5
// 284.327 us; speedup vs baseline: 19.9373x; 1.2686x over previous
//
#include <hip/hip_runtime.h>
#include <cstddef>
#include <cstdint>

#define NNODES 50000
#define NEDGES 800000
#define FDIM   256

#define SCAN_BLOCKS 256
#define SCAN_CHUNK  ((NNODES + SCAN_BLOCKS - 1) / SCAN_BLOCKS)   // 196

typedef __attribute__((ext_vector_type(8))) short short8;
typedef __attribute__((ext_vector_type(8))) unsigned short ushort8;
typedef __attribute__((ext_vector_type(4))) float f32x4;

__device__ __forceinline__ float leaky_exp(float a) {
    float e = a > 0.f ? a : 0.2f * a;
    return __expf(e);
}
__device__ __forceinline__ unsigned short f2bf(float f) {
    uint32_t u = __builtin_bit_cast(uint32_t, f);
    u += 0x7fffu + ((u >> 16) & 1u);               // RNE
    return (unsigned short)(u >> 16);
}
__device__ __forceinline__ float bf2f(unsigned short h) {
    uint32_t u = ((uint32_t)h) << 16;
    return __builtin_bit_cast(float, u);
}
__device__ __forceinline__ float bflo(uint32_t u) {
    return __builtin_bit_cast(float, u << 16);
}
__device__ __forceinline__ float bfhi(uint32_t u) {
    return __builtin_bit_cast(float, u & 0xffff0000u);
}
__device__ __forceinline__ float rlanef(float v, int l) {
    return __builtin_bit_cast(float,
        __builtin_amdgcn_readlane(__builtin_bit_cast(int, v), l));
}

// ---------------- fp32 -> bf16 bulk convert (8 elems/thread) ----------------
__global__ __launch_bounds__(256) void cvt_k(const float* __restrict__ in,
                                             unsigned short* __restrict__ out,
                                             int n8) {
    int i = blockIdx.x * 256 + threadIdx.x;
    if (i >= n8) return;
    const float4* p = (const float4*)in + (size_t)i * 2;
    float4 a = p[0], b = p[1];
    ushort8 r;
    r[0] = f2bf(a.x); r[1] = f2bf(a.y); r[2] = f2bf(a.z); r[3] = f2bf(a.w);
    r[4] = f2bf(b.x); r[5] = f2bf(b.y); r[6] = f2bf(b.z); r[7] = f2bf(b.w);
    *(ushort8*)(out + (size_t)i * 8) = r;
}

// ------------- W[256][256] -> Wt[n][k] bf16 (transpose + convert) -------------
__global__ __launch_bounds__(256) void wprep_k(const float* __restrict__ W,
                                               unsigned short* __restrict__ Wt) {
    int n = blockIdx.x, k = threadIdx.x;
    Wt[n * 256 + k] = f2bf(W[k * 256 + n]);
}

// --------- bf16 MFMA GEMM: C[M,256] = A[M,256] @ Bt[256,256]^T, bf16 out ---------
__global__ __launch_bounds__(256) void gemm_mfma(const unsigned short* __restrict__ A,
                                                 const unsigned short* __restrict__ Bt,
                                                 unsigned short* __restrict__ C, int M) {
    __shared__ unsigned short As[128 * 64];
    __shared__ unsigned short Bs[128 * 64];
    const int t = threadIdx.x;
    const int lane = t & 63, wid = t >> 6;
    const int wr = wid >> 1, wc = wid & 1;
    const int bm = blockIdx.x * 128;
    const int bn = blockIdx.y * 128;
    f32x4 acc[4][4] = {};
    const int lrow = t >> 3, lslot = t & 7;
    for (int k0 = 0; k0 < 256; k0 += 64) {
        __syncthreads();
#pragma unroll
        for (int i = 0; i < 4; ++i) {
            int row = lrow + 32 * i;
            int ga = bm + row; ga = ga < M ? ga : M - 1;
            uint4 av = *(const uint4*)(A + (size_t)ga * FDIM + k0 + lslot * 8);
            *(uint4*)(As + row * 64 + ((lslot ^ (row & 7)) << 3)) = av;
            uint4 bv = *(const uint4*)(Bt + (size_t)(bn + row) * FDIM + k0 + lslot * 8);
            *(uint4*)(Bs + row * 64 + ((lslot ^ (row & 7)) << 3)) = bv;
        }
        __syncthreads();
#pragma unroll
        for (int ks = 0; ks < 2; ++ks) {
            const int kq = ks * 4 + (lane >> 4);
            short8 a[4], b[4];
#pragma unroll
            for (int f = 0; f < 4; ++f) {
                int ra = wr * 64 + f * 16 + (lane & 15);
                a[f] = *(const short8*)(As + ra * 64 + ((kq ^ (ra & 7)) << 3));
                int rb = wc * 64 + f * 16 + (lane & 15);
                b[f] = *(const short8*)(Bs + rb * 64 + ((kq ^ (rb & 7)) << 3));
            }
#pragma unroll
            for (int mf = 0; mf < 4; ++mf)
#pragma unroll
                for (int nf = 0; nf < 4; ++nf)
                    acc[mf][nf] = __builtin_amdgcn_mfma_f32_16x16x32_bf16(
                        a[mf], b[nf], acc[mf][nf], 0, 0, 0);
        }
    }
    const int col0 = bn + wc * 64 + (lane & 15);
    const int row00 = bm + wr * 64 + (lane >> 4) * 4;
#pragma unroll
    for (int mf = 0; mf < 4; ++mf)
#pragma unroll
        for (int nf = 0; nf < 4; ++nf) {
            f32x4 v = acc[mf][nf];
            int col = col0 + nf * 16;
#pragma unroll
            for (int r = 0; r < 4; ++r) {
                int row = row00 + mf * 16 + r;
                if (row < M) C[(size_t)row * FDIM + col] = f2bf(v[r]);
            }
        }
}

// ------------- attention logits from bf16 xp; wave per node -------------
template <int H>
__global__ __launch_bounds__(256) void aprep_k(const unsigned short* __restrict__ xp,
                                               const float* __restrict__ atts,
                                               const float* __restrict__ attd,
                                               float* __restrict__ as_,
                                               float* __restrict__ ad_) {
    const int lane = threadIdx.x & 63;
    const int n = blockIdx.x * 4 + (threadIdx.x >> 6);
    if (n >= NNODES) return;
    const int c = lane << 2;
    ushort4 u = *(const ushort4*)(xp + (size_t)n * FDIM + c);
    float v0 = bf2f(u.x), v1 = bf2f(u.y), v2 = bf2f(u.z), v3 = bf2f(u.w);
    float4 s4 = *(const float4*)(atts + c);
    float4 d4 = *(const float4*)(attd + c);
    float ss = v0 * s4.x + v1 * s4.y + v2 * s4.z + v3 * s4.w;
    float sd = v0 * d4.x + v1 * d4.y + v2 * d4.z + v3 * d4.w;
    constexpr int G = 64 / H;
#pragma unroll
    for (int off = 1; off < G; off <<= 1) {
        ss += __shfl_xor(ss, off);
        sd += __shfl_xor(sd, off);
    }
    if ((lane & (G - 1)) == 0) {
        int h = lane / G;
        as_[n * H + h] = ss;
        ad_[n * H + h] = sd;
    }
}

// ---------------- CSR build: histogram -> 3-phase scan -> scatter ----------------
__global__ __launch_bounds__(256) void hist_k(const int* __restrict__ ei,
                                              int* __restrict__ deg) {
    int e = blockIdx.x * 256 + threadIdx.x;
    if (e < NEDGES) atomicAdd(&deg[ei[NEDGES + e]], 1);
}

// A: per-block chunk sums
__global__ __launch_bounds__(256) void scanA_k(const int* __restrict__ deg,
                                               int* __restrict__ bsum) {
    const int b = blockIdx.x, t = threadIdx.x;
    const int i = b * SCAN_CHUNK + t;
    int v = (t < SCAN_CHUNK && i < NNODES) ? deg[i] : 0;
#pragma unroll
    for (int off = 1; off < 64; off <<= 1) v += __shfl_xor(v, off);
    __shared__ int ws[4];
    if ((t & 63) == 0) ws[t >> 6] = v;
    __syncthreads();
    if (t == 0) bsum[b] = ws[0] + ws[1] + ws[2] + ws[3];
}

// B: exclusive scan of 256 block sums (single block)
__global__ __launch_bounds__(256) void scanB_k(const int* __restrict__ bsum,
                                               int* __restrict__ boff,
                                               int* __restrict__ rowptr) {
    const int t = threadIdx.x;
    const int lane = t & 63, wid = t >> 6;
    int orig = bsum[t];
    int v = orig;
#pragma unroll
    for (int off = 1; off < 64; off <<= 1) {
        int u = __shfl_up(v, off);
        if (lane >= off) v += u;
    }
    __shared__ int ws[4], wo[4];
    if (lane == 63) ws[wid] = v;
    __syncthreads();
    if (t == 0) {
        int a = 0;
        for (int k = 0; k < 4; ++k) { wo[k] = a; a += ws[k]; }
        rowptr[NNODES] = a;
    }
    __syncthreads();
    boff[t] = wo[wid] + v - orig;
}

// C: block-local exclusive scan + block offset -> rowptr
__global__ __launch_bounds__(256) void scanC_k(const int* __restrict__ deg,
                                               const int* __restrict__ boff,
                                               int* __restrict__ rowptr) {
    const int b = blockIdx.x, t = threadIdx.x;
    const int i = b * SCAN_CHUNK + t;
    const bool ok = (t < SCAN_CHUNK && i < NNODES);
    int orig = ok ? deg[i] : 0;
    int v = orig;
    const int lane = t & 63, wid = t >> 6;
#pragma unroll
    for (int off = 1; off < 64; off <<= 1) {
        int u = __shfl_up(v, off);
        if (lane >= off) v += u;
    }
    __shared__ int ws[4], wo[4];
    if (lane == 63) ws[wid] = v;
    __syncthreads();
    if (t == 0) {
        int a = 0;
        for (int k = 0; k < 4; ++k) { wo[k] = a; a += ws[k]; }
    }
    __syncthreads();
    if (ok) rowptr[i] = boff[b] + wo[wid] + v - orig;
}

__global__ __launch_bounds__(256) void scatter_k(const int* __restrict__ ei,
                                                 const int* __restrict__ rowptr,
                                                 int* __restrict__ deg,
                                                 int* __restrict__ ssrc) {
    int e = blockIdx.x * 256 + threadIdx.x;
    if (e >= NEDGES) return;
    int s = ei[e], d = ei[NEDGES + e];
    int old = atomicSub(&deg[d], 1);
    ssrc[rowptr[d + 1] - old] = s;
}

// ---- layer-1 gather (H=4): strip-mined weights + shfl broadcast ----
__global__ __launch_bounds__(256) void gather1_k(const unsigned short* __restrict__ xp,
                                                 const float* __restrict__ as_,
                                                 const float* __restrict__ ad_,
                                                 const int* __restrict__ rowptr,
                                                 const int* __restrict__ ssrc,
                                                 const float* __restrict__ bias,
                                                 unsigned short* __restrict__ out) {
    const int lane = threadIdx.x & 63;
    const int n = blockIdx.x * 4 + (threadIdx.x >> 6);
    if (n >= NNODES) return;
    const int h = lane >> 4;            // head for feature lanes
    const int c = lane << 2;
    const int eloc = lane >> 2;         // strip edge slot (0..15)
    const int hh = lane & 3;            // strip head slot
    const float adW = ad_[n * 4 + hh];
    float a0 = 0.f, a1 = 0.f, a2 = 0.f, a3 = 0.f, den = 0.f;
    const int beg = rowptr[n], end = rowptr[n + 1];
    for (int base = beg; base < end; base += 16) {
        int my_e = base + eloc;
        float wv = 0.f; int sv = 0;
        if (my_e < end) {
            sv = ssrc[my_e];
            wv = leaky_exp(as_[sv * 4 + hh] + adW);
        }
        const int cnt = min(16, end - base);
        int e = 0;
        for (; e + 4 <= cnt; e += 4) {
            int s0 = __builtin_amdgcn_readlane(sv, (e + 0) << 2);
            int s1 = __builtin_amdgcn_readlane(sv, (e + 1) << 2);
            int s2 = __builtin_amdgcn_readlane(sv, (e + 2) << 2);
            int s3 = __builtin_amdgcn_readlane(sv, (e + 3) << 2);
            uint2 u0 = *(const uint2*)(xp + (((unsigned)s0 << 8) + (unsigned)c));
            uint2 u1 = *(const uint2*)(xp + (((unsigned)s1 << 8) + (unsigned)c));
            uint2 u2 = *(const uint2*)(xp + (((unsigned)s2 << 8) + (unsigned)c));
            uint2 u3 = *(const uint2*)(xp + (((unsigned)s3 << 8) + (unsigned)c));
            float w0 = __shfl(wv, ((e + 0) << 2) | h);
            float w1 = __shfl(wv, ((e + 1) << 2) | h);
            float w2 = __shfl(wv, ((e + 2) << 2) | h);
            float w3 = __shfl(wv, ((e + 3) << 2) | h);
            a0 += w0 * bflo(u0.x) + w1 * bflo(u1.x) + w2 * bflo(u2.x) + w3 * bflo(u3.x);
            a1 += w0 * bfhi(u0.x) + w1 * bfhi(u1.x) + w2 * bfhi(u2.x) + w3 * bfhi(u3.x);
            a2 += w0 * bflo(u0.y) + w1 * bflo(u1.y) + w2 * bflo(u2.y) + w3 * bflo(u3.y);
            a3 += w0 * bfhi(u0.y) + w1 * bfhi(u1.y) + w2 * bfhi(u2.y) + w3 * bfhi(u3.y);
            den += (w0 + w1) + (w2 + w3);
        }
        for (; e < cnt; ++e) {
            int s0 = __builtin_amdgcn_readlane(sv, e << 2);
            uint2 u0 = *(const uint2*)(xp + (((unsigned)s0 << 8) + (unsigned)c));
            float w0 = __shfl(wv, (e << 2) | h);
            a0 += w0 * bflo(u0.x); a1 += w0 * bfhi(u0.x);
            a2 += w0 * bflo(u0.y); a3 += w0 * bfhi(u0.y);
            den += w0;
        }
    }
    {   // self loop
        float w = leaky_exp(as_[n * 4 + h] + ad_[n * 4 + h]);
        uint2 u = *(const uint2*)(xp + (((unsigned)n << 8) + (unsigned)c));
        a0 += w * bflo(u.x); a1 += w * bfhi(u.x);
        a2 += w * bflo(u.y); a3 += w * bfhi(u.y);
        den += w;
    }
    const float inv = 1.f / (den + 1e-16f);
    float4 b4 = *(const float4*)(bias + c);
    float o[4] = {a0 * inv + b4.x, a1 * inv + b4.y,
                  a2 * inv + b4.z, a3 * inv + b4.w};
#pragma unroll
    for (int j = 0; j < 4; ++j) o[j] = o[j] > 0.f ? o[j] : __expf(o[j]) - 1.f;
    ushort4 r;
    r.x = f2bf(o[0]); r.y = f2bf(o[1]); r.z = f2bf(o[2]); r.w = f2bf(o[3]);
    *(ushort4*)(out + (size_t)n * FDIM + c) = r;
}

// ---- layer-2 gather (H=1): 64-edge strips, SGPR weight broadcast; +BN+LN ----
__global__ __launch_bounds__(256) void gather2_k(const unsigned short* __restrict__ xp,
                                                 const float* __restrict__ as_,
                                                 const float* __restrict__ ad_,
                                                 const int* __restrict__ rowptr,
                                                 const int* __restrict__ ssrc,
                                                 const float* __restrict__ bias,
                                                 const float* __restrict__ bng,
                                                 const float* __restrict__ bnb,
                                                 const float* __restrict__ bnm,
                                                 const float* __restrict__ bnv,
                                                 const float* __restrict__ lng,
                                                 const float* __restrict__ lnb,
                                                 float* __restrict__ out) {
    const int lane = threadIdx.x & 63;
    const int n = blockIdx.x * 4 + (threadIdx.x >> 6);
    if (n >= NNODES) return;
    const int c = lane << 2;
    const float adn = ad_[n];
    float a0 = 0.f, a1 = 0.f, a2 = 0.f, a3 = 0.f, den = 0.f;
    const int beg = rowptr[n], end = rowptr[n + 1];
    for (int base = beg; base < end; base += 64) {
        int my_e = base + lane;
        float wv = 0.f; int sv = 0;
        if (my_e < end) {
            sv = ssrc[my_e];
            wv = leaky_exp(as_[sv] + adn);
        }
        const int cnt = min(64, end - base);
        int e = 0;
        for (; e + 4 <= cnt; e += 4) {
            int s0 = __builtin_amdgcn_readlane(sv, e + 0);
            int s1 = __builtin_amdgcn_readlane(sv, e + 1);
            int s2 = __builtin_amdgcn_readlane(sv, e + 2);
            int s3 = __builtin_amdgcn_readlane(sv, e + 3);
            uint2 u0 = *(const uint2*)(xp + (((unsigned)s0 << 8) + (unsigned)c));
            uint2 u1 = *(const uint2*)(xp + (((unsigned)s1 << 8) + (unsigned)c));
            uint2 u2 = *(const uint2*)(xp + (((unsigned)s2 << 8) + (unsigned)c));
            uint2 u3 = *(const uint2*)(xp + (((unsigned)s3 << 8) + (unsigned)c));
            float w0 = rlanef(wv, e + 0);
            float w1 = rlanef(wv, e + 1);
            float w2 = rlanef(wv, e + 2);
            float w3 = rlanef(wv, e + 3);
            a0 += w0 * bflo(u0.x) + w1 * bflo(u1.x) + w2 * bflo(u2.x) + w3 * bflo(u3.x);
            a1 += w0 * bfhi(u0.x) + w1 * bfhi(u1.x) + w2 * bfhi(u2.x) + w3 * bfhi(u3.x);
            a2 += w0 * bflo(u0.y) + w1 * bflo(u1.y) + w2 * bflo(u2.y) + w3 * bflo(u3.y);
            a3 += w0 * bfhi(u0.y) + w1 * bfhi(u1.y) + w2 * bfhi(u2.y) + w3 * bfhi(u3.y);
            den += (w0 + w1) + (w2 + w3);
        }
        for (; e < cnt; ++e) {
            int s0 = __builtin_amdgcn_readlane(sv, e);
            uint2 u0 = *(const uint2*)(xp + (((unsigned)s0 << 8) + (unsigned)c));
            float w0 = rlanef(wv, e);
            a0 += w0 * bflo(u0.x); a1 += w0 * bfhi(u0.x);
            a2 += w0 * bflo(u0.y); a3 += w0 * bfhi(u0.y);
            den += w0;
        }
    }
    {   // self loop
        float w = leaky_exp(as_[n] + adn);
        uint2 u = *(const uint2*)(xp + (((unsigned)n << 8) + (unsigned)c));
        a0 += w * bflo(u.x); a1 += w * bfhi(u.x);
        a2 += w * bflo(u.y); a3 += w * bfhi(u.y);
        den += w;
    }
    const float inv = 1.f / (den + 1e-16f);
    float vals[4] = {a0 * inv, a1 * inv, a2 * inv, a3 * inv};
#pragma unroll
    for (int j = 0; j < 4; ++j) {
        float o = vals[j] + bias[c + j];
        o = o > 0.f ? o : __expf(o) - 1.f;                             // ELU
        o = (o - bnm[c + j]) * rsqrtf(bnv[c + j] + 1e-5f) * bng[c + j]
            + bnb[c + j];                                              // BN
        vals[j] = o;
    }
    float s1 = vals[0] + vals[1] + vals[2] + vals[3];
    float s2 = vals[0] * vals[0] + vals[1] * vals[1] +
               vals[2] * vals[2] + vals[3] * vals[3];
#pragma unroll
    for (int off = 1; off < 64; off <<= 1) {
        s1 += __shfl_xor(s1, off);
        s2 += __shfl_xor(s2, off);
    }
    float mu  = s1 * (1.f / 256.f);
    float var = s2 * (1.f / 256.f) - mu * mu;
    float r   = rsqrtf(var + 1e-5f);
#pragma unroll
    for (int j = 0; j < 4; ++j)
        out[(size_t)n * FDIM + c + j] = (vals[j] - mu) * r * lng[c + j] + lnb[c + j];
}

extern "C" void kernel_launch(void* const* d_in, const int* in_sizes, int n_in,
                              void* d_out, int out_size, void* d_ws, size_t ws_size,
                              hipStream_t stream) {
    const float* x      = (const float*)d_in[0];
    const int*   ei     = (const int*)d_in[1];
    const float* W1     = (const float*)d_in[2];
    const float* atts1  = (const float*)d_in[3];
    const float* attd1  = (const float*)d_in[4];
    const float* bias1  = (const float*)d_in[5];
    const float* W2     = (const float*)d_in[6];
    const float* atts2  = (const float*)d_in[7];
    const float* attd2  = (const float*)d_in[8];
    const float* bias2  = (const float*)d_in[9];
    const float* bng    = (const float*)d_in[10];
    const float* bnb    = (const float*)d_in[11];
    const float* bnm    = (const float*)d_in[12];
    const float* bnv    = (const float*)d_in[13];
    const float* lng    = (const float*)d_in[14];
    const float* lnb    = (const float*)d_in[15];

    const size_t NF = (size_t)NNODES * FDIM;
    unsigned short* xpbf = (unsigned short*)d_ws;     // 25.6 MB
    unsigned short* xbf  = xpbf + NF;                 // 25.6 MB (x bf16, then h1)
    unsigned short* wt1  = xbf + NF;
    unsigned short* wt2  = wt1 + 65536;
    float* as1   = (float*)(wt2 + 65536);
    float* ad1   = as1 + (size_t)NNODES * 4;
    float* as2   = ad1 + (size_t)NNODES * 4;
    float* ad2   = as2 + NNODES;
    int*   deg    = (int*)(ad2 + NNODES);
    int*   rowptr = deg + NNODES;
    int*   bsum   = rowptr + (NNODES + 1);
    int*   boff   = bsum + SCAN_BLOCKS;
    int*   ssrc   = boff + SCAN_BLOCKS;
    float* outf  = (float*)d_out;

    const dim3 gemm_grid((NNODES + 127) / 128, 2);
    const int node_wave_blocks = (NNODES + 3) / 4;
    const int edge_thread_blocks = (NEDGES + 255) / 256;
    const int cvt_blocks = (int)((NF / 8 + 255) / 256);

    // ---- prep: conversions + CSR ----
    cvt_k<<<cvt_blocks, 256, 0, stream>>>(x, xbf, (int)(NF / 8));
    wprep_k<<<256, 256, 0, stream>>>(W1, wt1);
    wprep_k<<<256, 256, 0, stream>>>(W2, wt2);
    hipMemsetAsync(deg, 0, NNODES * sizeof(int), stream);
    hist_k<<<edge_thread_blocks, 256, 0, stream>>>(ei, deg);
    scanA_k<<<SCAN_BLOCKS, 256, 0, stream>>>(deg, bsum);
    scanB_k<<<1, 256, 0, stream>>>(bsum, boff, rowptr);
    scanC_k<<<SCAN_BLOCKS, 256, 0, stream>>>(deg, boff, rowptr);
    scatter_k<<<edge_thread_blocks, 256, 0, stream>>>(ei, rowptr, deg, ssrc);

    // ---- layer 1 ----
    gemm_mfma<<<gemm_grid, 256, 0, stream>>>(xbf, wt1, xpbf, NNODES);
    aprep_k<4><<<node_wave_blocks, 256, 0, stream>>>(xpbf, atts1, attd1, as1, ad1);
    gather1_k<<<node_wave_blocks, 256, 0, stream>>>(xpbf, as1, ad1, rowptr, ssrc,
                                                    bias1, xbf);

    // ---- layer 2 ----
    gemm_mfma<<<gemm_grid, 256, 0, stream>>>(xbf, wt2, xpbf, NNODES);
    aprep_k<1><<<node_wave_blocks, 256, 0, stream>>>(xpbf, atts2, attd2, as2, ad2);
    gather2_k<<<node_wave_blocks, 256, 0, stream>>>(xpbf, as2, ad2, rowptr, ssrc,
                                                    bias2, bng, bnb, bnm, bnv,
                                                    lng, lnb, outf);
}